// Round 5
// baseline (298.270 us; speedup 1.0000x reference)
//
#include <hip/hip_runtime.h>

#define NH    16
#define HD    64
#define SQ    2048
#define SKV   2048
#define DM    1024

typedef __attribute__((ext_vector_type(8))) __bf16 bf16x8;
typedef __attribute__((ext_vector_type(4))) __bf16 bf16x4;
typedef __attribute__((ext_vector_type(4))) float  f32x4;
typedef __attribute__((ext_vector_type(4))) short  s16x4;

// async global->LDS, 16B per lane; LDS dest = wave-uniform base + lane*16
#define ASYNC16(gp, lp)                                                        \
    __builtin_amdgcn_global_load_lds(                                          \
        (const __attribute__((address_space(1))) void*)(gp),                   \
        (__attribute__((address_space(3))) void*)(lp), 16, 0, 0)

// exp(x/32) = exp2(x * log2(e)/32): single v_mul + v_exp_f32
#if __has_builtin(__builtin_amdgcn_exp2f)
#define EXPS(x) __builtin_amdgcn_exp2f((x) * 0.04508422f)
#else
#define EXPS(x) __expf((x) * 0.03125f)
#endif

// K=16 bf16 MFMA: S^T output fragment IS its A-operand layout (in-register E)
#if __has_builtin(__builtin_amdgcn_mfma_f32_16x16x16bf16_1k)
static __device__ __forceinline__ f32x4 mfma16(bf16x4 a, bf16x4 b, f32x4 c) {
    return __builtin_amdgcn_mfma_f32_16x16x16bf16_1k(
        __builtin_bit_cast(s16x4, a), __builtin_bit_cast(s16x4, b), c, 0, 0, 0);
}
#else
static __device__ __forceinline__ f32x4 mfma16(bf16x4 a, bf16x4 b, f32x4 c) {
    asm volatile("s_nop 1\n\tv_mfma_f32_16x16x16_bf16 %0, %1, %2, %0"
                 : "+v"(c) : "v"(a), "v"(b));
    return c;
}
#endif

// swizzled LDS tile: 64 elems/row, 8 chunks of 8 bf16; chunk' = chunk ^ (row&7)
static __device__ __forceinline__ int swz(int row, int chunk) {
    return (row << 6) + (((chunk) ^ (row & 7)) << 3);
}

static __device__ __forceinline__ bf16x4 cvt4(float4 v) {
    bf16x4 r;
    r[0] = (__bf16)v.x; r[1] = (__bf16)v.y; r[2] = (__bf16)v.z; r[3] = (__bf16)v.w;
    return r;
}

// ---------------------------------------------------------------------------
// kprep_all: Q-prep, K-prep, W-convert in one launch
// ---------------------------------------------------------------------------
__global__ void kprep_all(const float* __restrict__ q, const float* __restrict__ k,
                          const float* __restrict__ W,
                          __bf16* __restrict__ Qh, __bf16* __restrict__ Kh,
                          __bf16* __restrict__ Wb) {
    int bid = blockIdx.x;
    if (bid < 8192) {
        const float* src = (bid < 4096) ? q : k;
        __bf16* dst = (bid < 4096) ? Qh : Kh;
        size_t g = (size_t)(bid & 4095) * 256 + threadIdx.x;
        size_t o = g * 8;
        int c  = (int)(o & 63);
        int s  = (int)((o >> 6) & 2047);
        int bh = (int)(o >> 17);
        int b = bh >> 4, h = bh & 15;
        const float* p = src + ((size_t)(b * SQ + s)) * DM + h * HD + c;
        float4 v0 = *(const float4*)p;
        float4 v1 = *(const float4*)(p + 4);
        bf16x8 r;
        r[0] = (__bf16)v0.x; r[1] = (__bf16)v0.y; r[2] = (__bf16)v0.z; r[3] = (__bf16)v0.w;
        r[4] = (__bf16)v1.x; r[5] = (__bf16)v1.y; r[6] = (__bf16)v1.z; r[7] = (__bf16)v1.w;
        *(bf16x8*)(dst + o) = r;
    } else {
        int i = (bid - 8192) * 256 + threadIdx.x;
        float4 v = *(const float4*)(W + (size_t)i * 4);
        *(bf16x4*)(Wb + (size_t)i * 4) = cvt4(v);
    }
}

// ---------------------------------------------------------------------------
// kz: Z[k] = sum_q exp(QK^T/32); epilogue writes Vt[bh][d][k] = bf16(V/Z)
// k-block 128 -> grid (64 bh, 16 kb) = 1024 blocks = 4 blocks/CU.
// K fragments resident in registers (32 k-cols per wave).
// ---------------------------------------------------------------------------
__global__ __launch_bounds__(256, 4) void kz(const __bf16* __restrict__ Qh,
                                             const __bf16* __restrict__ Kh,
                                             const float* __restrict__ v,
                                             __bf16* __restrict__ Vt) {
    const int bh = blockIdx.x;
    const int kb = blockIdx.y;
    const int b = bh >> 4, h = bh & 15;
    const int t = threadIdx.x;
    const int w = t >> 6, lane = t & 63;
    const int lo16 = lane & 15, quad = lane >> 4;
    const int wub = (t & 192) << 3;

    __shared__ __bf16 Ks[128 * 64];
    __shared__ __bf16 Qs[2][64 * 64];
    __shared__ float  Zs[128];

    const __bf16* kbase = Kh + ((size_t)bh * SKV + kb * 128) * HD;
    const __bf16* qbase = Qh + (size_t)bh * SQ * HD;

    // stage K 128x64 + Q tile 0
#pragma unroll
    for (int i = 0; i < 4; ++i) {
        int ci = i * 256 + t;
        int row = ci >> 3;
        int c = (ci & 7) ^ (row & 7);
        ASYNC16(kbase + row * 64 + c * 8, &Ks[i * 2048 + wub]);
    }
#pragma unroll
    for (int i = 0; i < 2; ++i) {
        int ci = i * 256 + t;
        int row = ci >> 3;
        int c = (ci & 7) ^ (row & 7);
        ASYNC16(qbase + row * 64 + c * 8, &Qs[0][i * 2048 + wub]);
    }
    __syncthreads();

    // hoist K fragments (B-operand: n = k-col, kdim = d); wave owns 32 k-cols
    bf16x8 bk[2][2];
#pragma unroll
    for (int nt = 0; nt < 2; ++nt)
#pragma unroll
        for (int dh = 0; dh < 2; ++dh)
            bk[nt][dh] = *(const bf16x8*)(&Ks[swz(w * 32 + nt * 16 + lo16, dh * 4 + quad)]);

    float zacc[2] = {0.f, 0.f};

    for (int qt = 0; qt < 32; ++qt) {
        const int cur = qt & 1, nxt = cur ^ 1;
        if (qt < 31) {
#pragma unroll
            for (int i = 0; i < 2; ++i) {
                int ci = i * 256 + t;
                int row = ci >> 3;
                int c = (ci & 7) ^ (row & 7);
                ASYNC16(qbase + (size_t)(qt + 1) * 64 * HD + row * 64 + c * 8,
                        &Qs[nxt][i * 2048 + wub]);
            }
        }

#pragma unroll
        for (int mt = 0; mt < 4; ++mt) {
            bf16x8 aq0 = *(const bf16x8*)(&Qs[cur][swz(mt * 16 + lo16, quad)]);
            bf16x8 aq1 = *(const bf16x8*)(&Qs[cur][swz(mt * 16 + lo16, 4 + quad)]);
#pragma unroll
            for (int nt = 0; nt < 2; ++nt) {
                f32x4 acc = {0.f, 0.f, 0.f, 0.f};
                acc = __builtin_amdgcn_mfma_f32_16x16x32_bf16(aq0, bk[nt][0], acc, 0, 0, 0);
                acc = __builtin_amdgcn_mfma_f32_16x16x32_bf16(aq1, bk[nt][1], acc, 0, 0, 0);
                zacc[nt] += EXPS(acc[0]) + EXPS(acc[1]) + EXPS(acc[2]) + EXPS(acc[3]);
            }
        }
        __syncthreads();
    }

#pragma unroll
    for (int nt = 0; nt < 2; ++nt) {
        float s = zacc[nt];
        s += __shfl_xor(s, 16, 64);
        s += __shfl_xor(s, 32, 64);
        if (lane < 16) Zs[w * 32 + nt * 16 + lane] = s;
    }
    __syncthreads();

    // epilogue: Vt[bh][d][k] = bf16(V[k][d]/Z[k]); thread -> (k = t&127, d-half)
    {
        int kk = t & 127, dh2 = t >> 7;
        float rz = 1.0f / Zs[kk];
        int kfull = kb * 128 + kk;
        const float* vrow = v + ((size_t)(b * SKV) + kfull) * DM + h * HD + dh2 * 32;
        size_t vtb = (size_t)bh * HD * SKV + (size_t)(dh2 * 32) * SKV + kfull;
#pragma unroll
        for (int dc = 0; dc < 2; ++dc) {
            float4 a0 = *(const float4*)(vrow + dc * 16 + 0);
            float4 a1 = *(const float4*)(vrow + dc * 16 + 4);
            float4 a2 = *(const float4*)(vrow + dc * 16 + 8);
            float4 a3 = *(const float4*)(vrow + dc * 16 + 12);
            float tmp[16] = {a0.x, a0.y, a0.z, a0.w, a1.x, a1.y, a1.z, a1.w,
                             a2.x, a2.y, a2.z, a2.w, a3.x, a3.y, a3.z, a3.w};
#pragma unroll
            for (int j = 0; j < 16; ++j)
                Vt[vtb + (size_t)(dc * 16 + j) * SKV] = (__bf16)(tmp[j] * rz);
        }
    }
}

// ---------------------------------------------------------------------------
// kattn: O[q,:] = sum_k exp(S[q,k]) * Vt[:,k]   (Vt pre-scaled by 1/Z)
// S^T via 16x16x32 -> E stays IN REGISTERS (S^T C-layout == K=16 A-layout)
// -> PV via 16x16x16. No E LDS round-trip. grid (64 bh, 8 qb).
// ---------------------------------------------------------------------------
__global__ __launch_bounds__(256, 2) void kattn(const __bf16* __restrict__ Qh,
                                                const __bf16* __restrict__ Kh,
                                                const __bf16* __restrict__ Vt,
                                                __bf16* __restrict__ O) {
    const int bh = blockIdx.x;
    const int qb = blockIdx.y;
    const int b = bh >> 4, h = bh & 15;
    const int t = threadIdx.x;
    const int w = t >> 6, lane = t & 63;
    const int lo16 = lane & 15, quad = lane >> 4;
    const int wub = (t & 192) << 3;

    __shared__ __bf16 Ks[2][64 * 64];
    __shared__ __bf16 Vts[2][64 * 64];
    __shared__ __bf16 Qstage[256 * 64];

    const __bf16* qgbase = Qh + ((size_t)bh * SQ + qb * 256) * HD;
    const __bf16* kgbase = Kh + (size_t)bh * SKV * HD;
    const __bf16* vtgbase = Vt + (size_t)bh * HD * SKV;

    // stage Q 256x64 + K/Vt tile 0
#pragma unroll
    for (int i = 0; i < 8; ++i) {
        int ci = i * 256 + t;
        int row = ci >> 3;
        int c = (ci & 7) ^ (row & 7);
        ASYNC16(qgbase + row * 64 + c * 8, &Qstage[i * 2048 + wub]);
    }
#pragma unroll
    for (int i = 0; i < 2; ++i) {
        int ci = i * 256 + t;
        int row = ci >> 3;
        int c = (ci & 7) ^ (row & 7);
        ASYNC16(kgbase + row * 64 + c * 8, &Ks[0][i * 2048 + wub]);
        ASYNC16(vtgbase + (size_t)row * SKV + c * 8, &Vts[0][i * 2048 + wub]);
    }
    __syncthreads();

    // Q fragments (B-operand of S^T: n = q, kdim = d), persist in registers
    bf16x8 qf[4][2];
#pragma unroll
    for (int qt = 0; qt < 4; ++qt)
#pragma unroll
        for (int dh = 0; dh < 2; ++dh)
            qf[qt][dh] = *(const bf16x8*)(&Qstage[swz(w * 64 + qt * 16 + lo16, dh * 4 + quad)]);

    f32x4 oacc[4][4];
    f32x4 zero = {0.f, 0.f, 0.f, 0.f};
#pragma unroll
    for (int qt = 0; qt < 4; ++qt)
#pragma unroll
        for (int nt = 0; nt < 4; ++nt)
            oacc[qt][nt] = zero;

    for (int kt = 0; kt < 32; ++kt) {
        const int cur = kt & 1, nxt = cur ^ 1;
        if (kt < 31) {
#pragma unroll
            for (int i = 0; i < 2; ++i) {
                int ci = i * 256 + t;
                int row = ci >> 3;
                int c = (ci & 7) ^ (row & 7);
                ASYNC16(kgbase + (size_t)(kt + 1) * 64 * HD + row * 64 + c * 8,
                        &Ks[nxt][i * 2048 + wub]);
                ASYNC16(vtgbase + (size_t)row * SKV + (kt + 1) * 64 + c * 8,
                        &Vts[nxt][i * 2048 + wub]);
            }
        }

        // S^T = K Q^T; E = exp -> bf16x4 fragments IN REGISTERS
        // S^T C-layout: lane holds D[key=quad*4+r][q=lo16]  ==  A-layout of
        // mfma_16x16x16 (A[m=lo16][k=quad*4+j]) with m=q, k=key.
        bf16x4 ef[4][4];                       // [qt][kg]
#pragma unroll
        for (int kg = 0; kg < 4; ++kg) {
            bf16x8 ak0 = *(const bf16x8*)(&Ks[cur][swz(kg * 16 + lo16, quad)]);
            bf16x8 ak1 = *(const bf16x8*)(&Ks[cur][swz(kg * 16 + lo16, 4 + quad)]);
#pragma unroll
            for (int qt = 0; qt < 4; ++qt) {
                f32x4 s = zero;
                s = __builtin_amdgcn_mfma_f32_16x16x32_bf16(ak0, qf[qt][0], s, 0, 0, 0);
                s = __builtin_amdgcn_mfma_f32_16x16x32_bf16(ak1, qf[qt][1], s, 0, 0, 0);
                bf16x4 e;
                e[0] = (__bf16)EXPS(s[0]);
                e[1] = (__bf16)EXPS(s[1]);
                e[2] = (__bf16)EXPS(s[2]);
                e[3] = (__bf16)EXPS(s[3]);
                ef[qt][kg] = e;
            }
        }

        // O += E @ Vt^T via K=16 MFMA; B-frag = b64 LDS read of Vts[d][k]
#pragma unroll
        for (int nt = 0; nt < 4; ++nt) {
#pragma unroll
            for (int kg = 0; kg < 4; ++kg) {
                int row = nt * 16 + lo16;
                int chunk = kg * 2 + (quad >> 1);
                bf16x4 bv = *(const bf16x4*)(
                    &Vts[cur][(row << 6) + ((chunk ^ (row & 7)) << 3) + ((quad & 1) << 2)]);
#pragma unroll
                for (int qt = 0; qt < 4; ++qt)
                    oacc[qt][nt] = mfma16(ef[qt][kg], bv, oacc[qt][nt]);
            }
        }
        __syncthreads();
    }

    // MFMA->VALU read safety margin for the asm-fallback path (cheap)
    asm volatile("s_nop 7\n\ts_nop 7" ::: );

    size_t obase = ((size_t)(b * SQ) + qb * 256 + w * 64) * DM + h * HD;
#pragma unroll
    for (int qt = 0; qt < 4; ++qt)
#pragma unroll
        for (int nt = 0; nt < 4; ++nt)
#pragma unroll
            for (int r = 0; r < 4; ++r)
                O[obase + (size_t)(qt * 16 + quad * 4 + r) * DM + nt * 16 + lo16] =
                    (__bf16)oacc[qt][nt][r];
}

// ---------------------------------------------------------------------------
// kproj: out[n, i] = sum_j A[n,j] * W[i,j] + b[i]   (NT GEMM, 128x128 tiles,
// double-buffered)
// ---------------------------------------------------------------------------
__global__ __launch_bounds__(256, 2) void kproj(const __bf16* __restrict__ A,
                                                const __bf16* __restrict__ Wb,
                                                const float* __restrict__ bias,
                                                float* __restrict__ out) {
    const int nb = blockIdx.x;
    const int mb = blockIdx.y;
    const int t = threadIdx.x;
    const int w = t >> 6, lane = t & 63;
    const int lo16 = lane & 15, quad = lane >> 4;
    const int wm = w & 1, wn = w >> 1;
    const int wub = (t & 192) << 3;

    __shared__ __bf16 As[2][128 * 64];
    __shared__ __bf16 Bs[2][128 * 64];

    f32x4 acc[4][4];
    f32x4 zero = {0.f, 0.f, 0.f, 0.f};
#pragma unroll
    for (int mt = 0; mt < 4; ++mt)
#pragma unroll
        for (int nt = 0; nt < 4; ++nt)
            acc[mt][nt] = zero;

    const __bf16* abase = A + (size_t)(mb * 128) * DM;
    const __bf16* wbase = Wb + (size_t)(nb * 128) * DM;

#pragma unroll
    for (int i = 0; i < 4; ++i) {
        int ci = i * 256 + t;
        int row = ci >> 3;
        int c = (ci & 7) ^ (row & 7);
        ASYNC16(abase + (size_t)row * DM + c * 8, &As[0][i * 2048 + wub]);
        ASYNC16(wbase + (size_t)row * DM + c * 8, &Bs[0][i * 2048 + wub]);
    }
    __syncthreads();

    for (int kt = 0; kt < 16; ++kt) {
        const int cur = kt & 1, nxt = cur ^ 1;
        if (kt < 15) {
#pragma unroll
            for (int i = 0; i < 4; ++i) {
                int ci = i * 256 + t;
                int row = ci >> 3;
                int c = (ci & 7) ^ (row & 7);
                ASYNC16(abase + (size_t)row * DM + (kt + 1) * 64 + c * 8, &As[nxt][i * 2048 + wub]);
                ASYNC16(wbase + (size_t)row * DM + (kt + 1) * 64 + c * 8, &Bs[nxt][i * 2048 + wub]);
            }
        }

#pragma unroll
        for (int ks = 0; ks < 2; ++ks) {
            bf16x8 av[4], bv[4];
#pragma unroll
            for (int mt = 0; mt < 4; ++mt)
                av[mt] = *(const bf16x8*)(&As[cur][swz(wm * 64 + mt * 16 + lo16, ks * 4 + quad)]);
#pragma unroll
            for (int nt = 0; nt < 4; ++nt)
                bv[nt] = *(const bf16x8*)(&Bs[cur][swz(wn * 64 + nt * 16 + lo16, ks * 4 + quad)]);
#pragma unroll
            for (int mt = 0; mt < 4; ++mt)
#pragma unroll
                for (int nt = 0; nt < 4; ++nt)
                    acc[mt][nt] = __builtin_amdgcn_mfma_f32_16x16x32_bf16(av[mt], bv[nt], acc[mt][nt], 0, 0, 0);
        }
        __syncthreads();
    }

    const int col0 = nb * 128 + wn * 64;
    const int row0 = mb * 128 + wm * 64;
#pragma unroll
    for (int nt = 0; nt < 4; ++nt) {
        float bb = bias[col0 + nt * 16 + lo16];
#pragma unroll
        for (int mt = 0; mt < 4; ++mt)
#pragma unroll
            for (int r = 0; r < 4; ++r)
                out[(size_t)(row0 + mt * 16 + quad * 4 + r) * DM + col0 + nt * 16 + lo16] =
                    acc[mt][nt][r] + bb;
    }
}

// ---------------------------------------------------------------------------
extern "C" void kernel_launch(void* const* d_in, const int* in_sizes, int n_in,
                              void* d_out, int out_size, void* d_ws, size_t ws_size,
                              hipStream_t stream) {
    const float* q    = (const float*)d_in[0];
    const float* k    = (const float*)d_in[1];
    const float* v    = (const float*)d_in[2];
    const float* W    = (const float*)d_in[3];
    const float* bias = (const float*)d_in[4];
    float* out = (float*)d_out;

    char* ws = (char*)d_ws;
    __bf16* Qh = (__bf16*)ws;                          // 16 MB
    __bf16* Kh = (__bf16*)(ws + (16u << 20));          // 16 MB
    __bf16* Vt = (__bf16*)(ws + (32u << 20));          // 16 MB
    __bf16* Wb = (__bf16*)(ws + (48u << 20));          // 2 MB
    __bf16* O  = (__bf16*)(ws + (50u << 20));          // 16 MB

    kprep_all<<<dim3(9216), 256, 0, stream>>>(q, k, W, Qh, Kh, Wb);
    kz       <<<dim3(64, 16), 256, 0, stream>>>(Qh, Kh, v, Vt);
    kattn    <<<dim3(64, 8), 256, 0, stream>>>(Qh, Kh, Vt, O);
    kproj    <<<dim3(8, 64), 256, 0, stream>>>(O, Wb, bias, out);
}